// Round 1
// baseline (1158.041 us; speedup 1.0000x reference)
//
#include <hip/hip_runtime.h>

#define NN 100000
#define NE 800000

// ---------------- CSR build ----------------

__global__ __launch_bounds__(256) void count_deg(const int* __restrict__ dst,
                                                 int* __restrict__ deg) {
  int e = blockIdx.x * 256 + threadIdx.x;
  if (e < NE) atomicAdd(&deg[dst[e]], 1);
}

__global__ __launch_bounds__(256) void alloc_rows(const int* __restrict__ deg,
                                                  int* __restrict__ row_start,
                                                  int* __restrict__ cursor,
                                                  float* __restrict__ inv_deg,
                                                  int* __restrict__ counter) {
  int n = blockIdx.x * 256 + threadIdx.x;
  int lane = threadIdx.x & 63;
  int d = (n < NN) ? deg[n] : 0;
  // inclusive wave scan of d
  int v = d;
#pragma unroll
  for (int off = 1; off < 64; off <<= 1) {
    int t = __shfl_up(v, off);
    if (lane >= off) v += t;
  }
  int total = __shfl(v, 63);
  int base = 0;
  if (lane == 0) base = atomicAdd(counter, total);
  base = __shfl(base, 0);
  if (n < NN) {
    int s = base + v - d;  // exclusive within wave
    row_start[n] = s;
    cursor[n] = s;
    inv_deg[n] = 1.0f / (float)((d > 1) ? d : 1);
  }
}

__global__ __launch_bounds__(256) void scatter_edges(const int* __restrict__ dst,
                                                     int* __restrict__ cursor,
                                                     int* __restrict__ edge_ids) {
  int e = blockIdx.x * 256 + threadIdx.x;
  if (e < NE) {
    int pos = atomicAdd(&cursor[dst[e]], 1);
    edge_ids[pos] = e;
  }
}

// ---------------- init h = emb[gate_type] ----------------

__global__ __launch_bounds__(256) void init_h(const int* __restrict__ gate,
                                              const float* __restrict__ emb,
                                              float* __restrict__ h) {
  int idx = blockIdx.x * 256 + threadIdx.x;  // n*64 + f
  if (idx < NN * 64) {
    int n = idx >> 6, f = idx & 63;
    h[idx] = emb[gate[n] * 64 + f];
  }
}

// ---------------- aggregation: hNs[n] = inv_deg * sum_e leaky(H1[src]+w·W1cols) --

__global__ __launch_bounds__(256) void aggregate(
    const float* __restrict__ H1, const int* __restrict__ row_start,
    const int* __restrict__ deg, const int* __restrict__ edge_ids,
    const int* __restrict__ src, const float* __restrict__ src_idx,
    const float* __restrict__ dst_idx, const float* __restrict__ rev,
    const float* __restrict__ W1,  // this layer, [64][67]
    const float* __restrict__ inv_deg, float* __restrict__ hNs) {
  int wid = (blockIdx.x * 256 + threadIdx.x) >> 6;  // one wave per node
  int lane = threadIdx.x & 63;
  if (wid >= NN) return;
  int n = wid;
  float w64 = W1[lane * 67 + 64];
  float w65 = W1[lane * 67 + 65];
  float w66 = W1[lane * 67 + 66];
  int s0 = row_start[n];
  int cnt = deg[n];
  float acc = 0.f;
  // 1-deep prefetch of the e -> s chain
  int e = (cnt > 0) ? edge_ids[s0] : 0;
  int s = (cnt > 0) ? src[e] : 0;
  for (int k = 0; k < cnt; ++k) {
    int e_n = e, s_n = s;
    if (k + 1 < cnt) {
      e_n = edge_ids[s0 + k + 1];
      s_n = src[e_n];
    }
    float si = src_idx[e], di = dst_idx[e], rv = rev[e];
    float v = H1[s * 64 + lane] + si * w64 + di * w65 + rv * w66;
    acc += (v >= 0.f) ? v : 0.01f * v;
    e = e_n;
    s = s_n;
  }
  hNs[n * 64 + lane] = acc * inv_deg[n];
}

// ---------------- node GEMM: C = act(A@W[:, :64]^T (+ B@W[:,64:128]^T) + bias) --
// W row-major [CO][ws]; KCH = number of 64-wide K chunks (1 or 2; chunk1 src = B)

template <int KCH, int CO, bool RELU, bool BIAS>
__global__ __launch_bounds__(256) void node_gemm(
    const float* __restrict__ A, const float* __restrict__ B,
    const float* __restrict__ W, int ws, const float* __restrict__ bias,
    float* __restrict__ C, int nrows) {
  constexpr int CPT = CO / 16;        // cols per thread: 4 (CO=64) or 2 (CO=32)
  __shared__ float AsT[64][132];      // [k][r], 128 rows + pad
  __shared__ float WT[64][CO];        // [k][c]
  const int tid = threadIdx.x;
  const int row0 = blockIdx.x * 128;
  const int tx = tid & 15, ty = tid >> 4;
  const int r0 = ty * 8;
  const int c0 = tx * CPT;
  float acc[8][CPT];
#pragma unroll
  for (int i = 0; i < 8; ++i)
#pragma unroll
    for (int j = 0; j < CPT; ++j) acc[i][j] = 0.f;

  for (int kc = 0; kc < KCH; ++kc) {
    const float* srcp = (kc == 0) ? A : B;
    if (kc) __syncthreads();  // previous chunk's reads done before restage
    // stage A chunk transposed: AsT[k][r]
#pragma unroll
    for (int it = 0; it < 8; ++it) {
      int idx = tid + it * 256;             // 128*16 = 2048
      int r = idx >> 4, kq = idx & 15;
      int nn = row0 + r;
      float4 av = {0.f, 0.f, 0.f, 0.f};
      if (nn < nrows) av = *(const float4*)&srcp[nn * 64 + 4 * kq];
      AsT[4 * kq + 0][r] = av.x;
      AsT[4 * kq + 1][r] = av.y;
      AsT[4 * kq + 2][r] = av.z;
      AsT[4 * kq + 3][r] = av.w;
    }
    // stage W chunk transposed: WT[k][c] = W[c][kc*64+k]
#pragma unroll
    for (int it = 0; it < (64 * CO) / 256; ++it) {
      int idx = tid + it * 256;
      int c = idx % CO;
      int k = idx / CO;
      WT[k][c] = W[c * ws + kc * 64 + k];
    }
    __syncthreads();
#pragma unroll 8
    for (int k = 0; k < 64; ++k) {
      float4 a0 = *(const float4*)&AsT[k][r0];
      float4 a1 = *(const float4*)&AsT[k][r0 + 4];
      float a[8] = {a0.x, a0.y, a0.z, a0.w, a1.x, a1.y, a1.z, a1.w};
      float b[CPT];
      if constexpr (CPT == 4) {
        float4 bb = *(const float4*)&WT[k][c0];
        b[0] = bb.x; b[1] = bb.y; b[2] = bb.z; b[3] = bb.w;
      } else {
        float2 bb = *(const float2*)&WT[k][c0];
        b[0] = bb.x; b[1] = bb.y;
      }
#pragma unroll
      for (int i = 0; i < 8; ++i)
#pragma unroll
        for (int j = 0; j < CPT; ++j) acc[i][j] += a[i] * b[j];
    }
    __syncthreads();
  }
  // epilogue
#pragma unroll
  for (int i = 0; i < 8; ++i) {
    int nn = row0 + r0 + i;
    if (nn < nrows) {
      float v[CPT];
#pragma unroll
      for (int j = 0; j < CPT; ++j) {
        v[j] = acc[i][j];
        if (BIAS) v[j] += bias[c0 + j];
        if (RELU) v[j] = fmaxf(v[j], 0.f);
      }
      if constexpr (CPT == 4) {
        float4 o = {v[0], v[1], v[2], v[3]};
        *(float4*)&C[nn * CO + c0] = o;
      } else {
        float2 o = {v[0], v[1]};
        *(float2*)&C[nn * CO + c0] = o;
      }
    }
  }
}

// ---------------- launcher ----------------

extern "C" void kernel_launch(void* const* d_in, const int* in_sizes, int n_in,
                              void* d_out, int out_size, void* d_ws, size_t ws_size,
                              hipStream_t stream) {
  const int* gate = (const int*)d_in[0];
  const int* src = (const int*)d_in[1];
  const int* dst = (const int*)d_in[2];
  const float* src_idx = (const float*)d_in[3];
  const float* dst_idx = (const float*)d_in[4];
  const float* rev = (const float*)d_in[5];
  const float* emb = (const float*)d_in[6];
  const float* W1 = (const float*)d_in[7];
  const float* W2 = (const float*)d_in[8];
  const float* b2 = (const float*)d_in[9];
  const float* Wl1 = (const float*)d_in[10];
  const float* bl1 = (const float*)d_in[11];
  const float* Wl2 = (const float*)d_in[12];
  const float* bl2 = (const float*)d_in[13];
  float* out = (float*)d_out;

  char* ws = (char*)d_ws;
  float* h = (float*)(ws + 0);            // 25.6 MB
  float* H1 = (float*)(ws + 25600000);    // 25.6 MB
  float* hNs = (float*)(ws + 51200000);   // 25.6 MB
  float* invd = (float*)(ws + 76800000);  // 0.4 MB
  int* deg = (int*)(ws + 77200000);       // 0.4 MB
  int* rowst = (int*)(ws + 77600000);     // 0.4 MB
  int* cursor = (int*)(ws + 78000000);    // 0.4 MB
  int* eids = (int*)(ws + 78400000);      // 3.2 MB
  int* counter = (int*)(ws + 81600000);   // 4 B

  hipMemsetAsync(deg, 0, NN * 4, stream);
  hipMemsetAsync(counter, 0, 4, stream);
  count_deg<<<3125, 256, 0, stream>>>(dst, deg);
  alloc_rows<<<391, 256, 0, stream>>>(deg, rowst, cursor, invd, counter);
  scatter_edges<<<3125, 256, 0, stream>>>(dst, cursor, eids);
  init_h<<<25000, 256, 0, stream>>>(gate, emb, h);

  for (int i = 0; i < 5; ++i) {
    const float* W1i = W1 + i * 64 * 67;
    const float* W2i = W2 + i * 64 * 128;
    const float* b2i = b2 + i * 64;
    // H1 = h @ W1[:, :64]^T
    node_gemm<1, 64, false, false><<<782, 256, 0, stream>>>(
        h, nullptr, W1i, 67, nullptr, H1, NN);
    // hNs = inv_deg * segsum(leaky(H1[src] + w-part))
    aggregate<<<25000, 256, 0, stream>>>(H1, rowst, deg, eids, src, src_idx,
                                         dst_idx, rev, W1i, invd, hNs);
    // h = relu(h @ W2[:, :64]^T + hNs @ W2[:, 64:]^T + b2)  (in-place safe)
    node_gemm<2, 64, true, true><<<782, 256, 0, stream>>>(
        h, hNs, W2i, 128, b2i, h, NN);
  }
  // final: t = relu(h @ Wl1^T + bl1) -> reuse H1; out = t @ Wl2^T + bl2
  node_gemm<1, 64, true, true><<<782, 256, 0, stream>>>(
      h, nullptr, Wl1, 64, bl1, H1, NN);
  node_gemm<1, 32, false, true><<<782, 256, 0, stream>>>(
      H1, nullptr, Wl2, 64, bl2, out, NN);
}

// Round 3
// 542.051 us; speedup vs baseline: 2.1364x; 2.1364x over previous
//
#include <hip/hip_runtime.h>

#define NN 100000
#define NE 800000

typedef __attribute__((ext_vector_type(8))) short short8;
typedef __attribute__((ext_vector_type(4))) float f32x4;

__device__ __forceinline__ unsigned short f2b(float x) {
  unsigned int u = __float_as_uint(x);
  u = u + 0x7fffu + ((u >> 16) & 1u);
  return (unsigned short)(u >> 16);
}
__device__ __forceinline__ float b2f(unsigned short s) {
  return __uint_as_float(((unsigned int)s) << 16);
}

// ---------------- CSR build ----------------

__global__ __launch_bounds__(256) void count_deg(const int* __restrict__ dst,
                                                 int* __restrict__ deg) {
  int e = blockIdx.x * 256 + threadIdx.x;
  if (e < NE) atomicAdd(&deg[dst[e]], 1);
}

__global__ __launch_bounds__(256) void alloc_rows(const int* __restrict__ deg,
                                                  int* __restrict__ row_start,
                                                  int* __restrict__ cursor,
                                                  float* __restrict__ inv_deg,
                                                  int* __restrict__ counter) {
  int n = blockIdx.x * 256 + threadIdx.x;
  int lane = threadIdx.x & 63;
  int d = (n < NN) ? deg[n] : 0;
  int v = d;
#pragma unroll
  for (int off = 1; off < 64; off <<= 1) {
    int t = __shfl_up(v, off);
    if (lane >= off) v += t;
  }
  int total = __shfl(v, 63);
  int base = 0;
  if (lane == 0) base = atomicAdd(counter, total);
  base = __shfl(base, 0);
  if (n < NN) {
    int s = base + v - d;
    row_start[n] = s;
    cursor[n] = s;
    inv_deg[n] = 1.0f / (float)((d > 1) ? d : 1);
  }
}

// packed CSR edge records: {src_as_float_bits, src_idx, dst_idx, rev}
__global__ __launch_bounds__(256) void scatter_edges(
    const int* __restrict__ dst, const int* __restrict__ src,
    const float* __restrict__ si, const float* __restrict__ di,
    const float* __restrict__ rv, int* __restrict__ cursor,
    float4* __restrict__ erec) {
  int e = blockIdx.x * 256 + threadIdx.x;
  if (e < NE) {
    int pos = atomicAdd(&cursor[dst[e]], 1);
    float4 r;
    r.x = __int_as_float(src[e]);
    r.y = si[e];
    r.z = di[e];
    r.w = rv[e];
    erec[pos] = r;
  }
}

// ---------------- init h = emb[gate_type] (bf16) ----------------

__global__ __launch_bounds__(256) void init_h(const int* __restrict__ gate,
                                              const float* __restrict__ emb,
                                              unsigned short* __restrict__ h) {
  int idx = blockIdx.x * 256 + threadIdx.x;  // n*16 + q (4 feats per thread)
  if (idx < NN * 16) {
    int n = idx >> 4, q = idx & 15;
    float4 v = *(const float4*)&emb[gate[n] * 64 + q * 4];
    ushort4 o = make_ushort4(f2b(v.x), f2b(v.y), f2b(v.z), f2b(v.w));
    *(ushort4*)&h[idx * 4] = o;
  }
}

// ------- aggregation: hNs[n] = inv_deg * sum_e leaky(H1[src] + w-part) -------
// 1 wave per node; quarter-waves process 4 edges per iteration; 4 feats/lane.

__global__ __launch_bounds__(256) void aggregate(
    const unsigned short* __restrict__ H1, const int* __restrict__ rowst,
    const int* __restrict__ deg, const float4* __restrict__ erec,
    const float* __restrict__ W1, const float* __restrict__ invd,
    unsigned short* __restrict__ hNs) {
  __shared__ float wcol[3][64];
  int tid = threadIdx.x;
  if (tid < 192) {
    int f = tid & 63, j = tid >> 6;
    wcol[j][f] = W1[f * 67 + 64 + j];
  }
  __syncthreads();
  int wid = (blockIdx.x * 256 + tid) >> 6;
  if (wid >= NN) return;
  int l = tid & 63;
  int q = l >> 4, fl = l & 15, f0 = fl * 4;
  float wa[4], wb[4], wc[4];
#pragma unroll
  for (int j = 0; j < 4; ++j) {
    wa[j] = wcol[0][f0 + j];
    wb[j] = wcol[1][f0 + j];
    wc[j] = wcol[2][f0 + j];
  }
  int s0 = rowst[wid], cnt = deg[wid];
  float acc[4] = {0.f, 0.f, 0.f, 0.f};

  float4 rc, rn;
  rc.x = rc.y = rc.z = rc.w = 0.f;
  rn.x = rn.y = rn.z = rn.w = 0.f;
  ushort4 hc = make_ushort4(0, 0, 0, 0);
  int iters = 0;
  if (cnt > q) {
    iters = (cnt - q + 3) >> 2;
    rc = erec[s0 + q];
    if (cnt > q + 4) rn = erec[s0 + q + 4];
    hc = *(const ushort4*)&H1[(size_t)__float_as_int(rc.x) * 64 + f0];
  }
  for (int k = 0; k < iters; ++k) {
    // prefetch record for k+2 and H1 row for k+1 (2-deep pipeline)
    float4 rn2;
    rn2.x = rn2.y = rn2.z = rn2.w = 0.f;
    if (q + 4 * (k + 2) < cnt) rn2 = erec[s0 + q + 4 * (k + 2)];
    ushort4 hn = make_ushort4(0, 0, 0, 0);
    if (q + 4 * (k + 1) < cnt)
      hn = *(const ushort4*)&H1[(size_t)__float_as_int(rn.x) * 64 + f0];
    // compute current edge
    float hx[4] = {b2f(hc.x), b2f(hc.y), b2f(hc.z), b2f(hc.w)};
#pragma unroll
    for (int j = 0; j < 4; ++j) {
      float v = hx[j] + rc.y * wa[j] + rc.z * wb[j] + rc.w * wc[j];
      acc[j] += (v >= 0.f) ? v : 0.01f * v;
    }
    rc = rn;
    hc = hn;
    rn = rn2;
  }
  // reduce quarters (xor 16, 32), then lane-quarter 0 writes
#pragma unroll
  for (int j = 0; j < 4; ++j) {
    acc[j] += __shfl_xor(acc[j], 16);
    acc[j] += __shfl_xor(acc[j], 32);
  }
  float idg = invd[wid];
  if (q == 0) {
    ushort4 o = make_ushort4(f2b(acc[0] * idg), f2b(acc[1] * idg),
                             f2b(acc[2] * idg), f2b(acc[3] * idg));
    *(ushort4*)&hNs[wid * 64 + f0] = o;
  }
}

// ------- node GEMM via MFMA: C = act(A@W[:,:64]^T (+ B@W[:,64:]^T) + bias) ---
// W fp32 row-major [CO][ws]; staged to LDS as bf16 with XOR swizzle.
// block = 256 (4 waves), 128 rows/block (2 row-tiles of 16 per wave).

template <int KCH, int CO, bool RELU, bool BIAS, bool OUTF32>
__global__ __launch_bounds__(256) void node_gemm(
    const unsigned short* __restrict__ A, const unsigned short* __restrict__ Bp,
    const float* __restrict__ W, int ws, const float* __restrict__ bias,
    void* __restrict__ Cv, int nrows) {
  constexpr int K = KCH * 64;
  __shared__ unsigned short Wlds[CO * K];
  const int tid = threadIdx.x;
#pragma unroll
  for (int it = 0; it < (CO * K) / 256; ++it) {
    int idx = tid + it * 256;
    int c = idx / K, k = idx % K;
    float v = W[c * ws + k];
    int byte = (c * K + k) * 2;
    byte ^= ((c & 7) << 4);
    *(unsigned short*)((char*)Wlds + byte) = f2b(v);
  }
  __syncthreads();
  const int w = tid >> 6, l = tid & 63;
  const int r16 = l & 15, kg = l >> 4;
  // B fragments from LDS (swizzled b128 reads, 2-way max conflict)
  short8 bfrag[2 * KCH][CO / 16];
#pragma unroll
  for (int kc = 0; kc < KCH; ++kc)
#pragma unroll
    for (int kk = 0; kk < 2; ++kk)
#pragma unroll
      for (int ct = 0; ct < CO / 16; ++ct) {
        int c = ct * 16 + r16;
        int k = kc * 64 + kk * 32 + kg * 8;
        int byte = (c * K + k) * 2;
        byte ^= ((c & 7) << 4);
        bfrag[kc * 2 + kk][ct] = *(const short8*)((const char*)Wlds + byte);
      }
  const int row_base = blockIdx.x * 128 + w * 32;
  f32x4 acc[2][CO / 16];
#pragma unroll
  for (int rt = 0; rt < 2; ++rt)
#pragma unroll
    for (int ct = 0; ct < CO / 16; ++ct) {
      f32x4 z = {0.f, 0.f, 0.f, 0.f};
      acc[rt][ct] = z;
    }
#pragma unroll
  for (int rt = 0; rt < 2; ++rt) {
    int arow = row_base + rt * 16 + r16;
    bool okr = arow < nrows;
#pragma unroll
    for (int kc = 0; kc < KCH; ++kc) {
      const unsigned short* sp = (kc == 0) ? A : Bp;
      short8 a0 = {0, 0, 0, 0, 0, 0, 0, 0};
      short8 a1 = {0, 0, 0, 0, 0, 0, 0, 0};
      if (okr) {
        a0 = *(const short8*)&sp[arow * 64 + kg * 8];
        a1 = *(const short8*)&sp[arow * 64 + 32 + kg * 8];
      }
#pragma unroll
      for (int ct = 0; ct < CO / 16; ++ct) {
        acc[rt][ct] = __builtin_amdgcn_mfma_f32_16x16x32_bf16(
            a0, bfrag[kc * 2][ct], acc[rt][ct], 0, 0, 0);
        acc[rt][ct] = __builtin_amdgcn_mfma_f32_16x16x32_bf16(
            a1, bfrag[kc * 2 + 1][ct], acc[rt][ct], 0, 0, 0);
      }
    }
  }
  // epilogue: C row = base + kg*4 + i, col = ct*16 + r16
#pragma unroll
  for (int rt = 0; rt < 2; ++rt)
#pragma unroll
    for (int ct = 0; ct < CO / 16; ++ct) {
      int col = ct * 16 + r16;
      float bv = BIAS ? bias[col] : 0.f;
#pragma unroll
      for (int i = 0; i < 4; ++i) {
        int row = row_base + rt * 16 + kg * 4 + i;
        if (row < nrows) {
          float v = acc[rt][ct][i] + bv;
          if (RELU) v = fmaxf(v, 0.f);
          if (OUTF32)
            ((float*)Cv)[row * CO + col] = v;
          else
            ((unsigned short*)Cv)[row * CO + col] = f2b(v);
        }
      }
    }
}

// ---------------- launcher ----------------

extern "C" void kernel_launch(void* const* d_in, const int* in_sizes, int n_in,
                              void* d_out, int out_size, void* d_ws, size_t ws_size,
                              hipStream_t stream) {
  const int* gate = (const int*)d_in[0];
  const int* src = (const int*)d_in[1];
  const int* dst = (const int*)d_in[2];
  const float* src_idx = (const float*)d_in[3];
  const float* dst_idx = (const float*)d_in[4];
  const float* rev = (const float*)d_in[5];
  const float* emb = (const float*)d_in[6];
  const float* W1 = (const float*)d_in[7];
  const float* W2 = (const float*)d_in[8];
  const float* b2 = (const float*)d_in[9];
  const float* Wl1 = (const float*)d_in[10];
  const float* bl1 = (const float*)d_in[11];
  const float* Wl2 = (const float*)d_in[12];
  const float* bl2 = (const float*)d_in[13];
  float* out = (float*)d_out;

  char* ws = (char*)d_ws;
  unsigned short* h = (unsigned short*)(ws + 0);           // 12.8 MB
  unsigned short* H1 = (unsigned short*)(ws + 12800000);   // 12.8 MB
  unsigned short* hNs = (unsigned short*)(ws + 25600000);  // 12.8 MB
  float4* erec = (float4*)(ws + 38400000);                 // 12.8 MB
  float* invd = (float*)(ws + 51200000);                   // 0.4 MB
  int* deg = (int*)(ws + 51600000);
  int* rowst = (int*)(ws + 52000000);
  int* cursor = (int*)(ws + 52400000);
  int* counter = (int*)(ws + 52800000);

  hipMemsetAsync(deg, 0, NN * 4, stream);
  hipMemsetAsync(counter, 0, 4, stream);
  count_deg<<<3125, 256, 0, stream>>>(dst, deg);
  alloc_rows<<<391, 256, 0, stream>>>(deg, rowst, cursor, invd, counter);
  scatter_edges<<<3125, 256, 0, stream>>>(dst, src, src_idx, dst_idx, rev,
                                          cursor, erec);
  init_h<<<6250, 256, 0, stream>>>(gate, emb, h);

  for (int i = 0; i < 5; ++i) {
    const float* W1i = W1 + i * 64 * 67;
    const float* W2i = W2 + i * 64 * 128;
    const float* b2i = b2 + i * 64;
    node_gemm<1, 64, false, false, false><<<782, 256, 0, stream>>>(
        h, nullptr, W1i, 67, nullptr, H1, NN);
    aggregate<<<25000, 256, 0, stream>>>(H1, rowst, deg, erec, W1i, invd, hNs);
    node_gemm<2, 64, true, true, false><<<782, 256, 0, stream>>>(
        h, hNs, W2i, 128, b2i, h, NN);
  }
  node_gemm<1, 64, true, true, false><<<782, 256, 0, stream>>>(
      h, nullptr, Wl1, 64, bl1, H1, NN);
  node_gemm<1, 32, false, true, true><<<782, 256, 0, stream>>>(
      H1, nullptr, Wl2, 64, bl2, out, NN);
}